// Round 1
// baseline (2168.145 us; speedup 1.0000x reference)
//
#include <hip/hip_runtime.h>
#include <stdint.h>

#define EPSF 1e-8f

// ---------------- workspace layout (fp32 element offsets) ----------------
constexpr size_t oP    = 0;                     // P   [8192*64]
constexpr size_t oW    = oP  + 8192*64;         // W   [4096*64]
constexpr size_t oG    = oW  + 4096*64;         // Gram[64*64]
constexpr size_t oM1   = oG  + 64*64;           // M1  [64*4096]
constexpr size_t oScal = oM1 + 64*4096;         // 4 u32: amax_w, amax_u, amax_v, amax_r
constexpr size_t nZero1= oScal + 4;             // zero range 1 (all accumulated bufs)
constexpr size_t oS    = nZero1;                // 64   (col norms / S)
constexpr size_t oLinv = oS + 64;               // 64*64
constexpr size_t oV    = oLinv + 64*64;         // V   [4096*64]
constexpr size_t oKV   = oV + 4096*64;          // KV  [64*4096]
constexpr size_t oU    = oKV + 64*4096;         // U   [8192*64]
constexpr size_t endF32= oU + 8192*64;
constexpr size_t bfByte= ((endF32*4 + 255)/256)*256;   // byte offset of bf16 region
constexpr size_t oVq   = 0;                     // Vq grid [64*4096] bf16
constexpr size_t oA    = oVq + 64*4096;         // A = [Rq | Uq]  [8192*4160] bf16
constexpr size_t oB    = oA + (size_t)8192*4160;// B = [Wq | M2T] [4096*4160] bf16
constexpr size_t endBF = oB + (size_t)4096*4160;
constexpr size_t WS_NEED = bfByte + endBF*2;
#define KT 4160

typedef float  f32x4  __attribute__((ext_vector_type(4)));
typedef __bf16 bf16x8 __attribute__((ext_vector_type(8)));

// ---------------- fp4 e2m1 quantization helpers ----------------
__device__ __forceinline__ float qlevel(float a){
  if (a <= 0.25f) return 0.0f;
  if (a <= 0.75f) return 0.5f;
  if (a <= 1.25f) return 1.0f;
  if (a <= 1.75f) return 1.5f;
  if (a <= 2.5f)  return 2.0f;
  if (a <= 3.5f)  return 3.0f;
  if (a <= 5.0f)  return 4.0f;
  return 6.0f;
}
__device__ __forceinline__ float qgrid(float v, float s){
  float y = v / s;              // match reference's division
  float l = qlevel(fabsf(y));
  return y < 0.0f ? -l : l;
}

// ---------------- small utility kernels ----------------
__global__ void k_zero(float* p, int n){
  for (int i = blockIdx.x*blockDim.x + threadIdx.x; i < n; i += gridDim.x*blockDim.x)
    p[i] = 0.0f;
}

__global__ void k_amax(const float* __restrict__ x, int n, unsigned* __restrict__ out){
  float m = 0.f;
  for (int i = blockIdx.x*blockDim.x + threadIdx.x; i < n; i += gridDim.x*blockDim.x)
    m = fmaxf(m, fabsf(x[i]));
  for (int o = 32; o > 0; o >>= 1) m = fmaxf(m, __shfl_down(m, o, 64));
  __shared__ float sm[4];
  int lane = threadIdx.x & 63, w = threadIdx.x >> 6;
  if (lane == 0) sm[w] = m;
  __syncthreads();
  if (threadIdx.x == 0)
    atomicMax(out, __float_as_uint(fmaxf(fmaxf(sm[0],sm[1]), fmaxf(sm[2],sm[3]))));
}

// ---------------- P += G @ Vc   (G[8192,4096], Vc[4096,64]) grid(64,8) ----------------
__global__ void k_gv(float* __restrict__ P, const float* __restrict__ G,
                     const float* __restrict__ Vc){
  __shared__ float Gt[128][33];
  __shared__ float Vt[32][64];
  int m0 = blockIdx.x * 128, d0 = blockIdx.y * 512;
  int t = threadIdx.x;
  int tm = t >> 3, tk = t & 7;
  float acc[4][8] = {};
  for (int dc = 0; dc < 512; dc += 32){
    for (int i = 0; i < 16; i++){
      int idx = i*256 + t; int r = idx >> 5, c = idx & 31;
      Gt[r][c] = G[(size_t)(m0 + r)*4096 + d0 + dc + c];
    }
    for (int i = 0; i < 8; i++){
      int idx = i*256 + t; int r = idx >> 6, c = idx & 63;
      Vt[r][c] = Vc[(size_t)(d0 + dc + r)*64 + c];
    }
    __syncthreads();
    for (int dd = 0; dd < 32; dd++){
      float g[4], v[8];
      #pragma unroll
      for (int a = 0; a < 4; a++) g[a] = Gt[tm*4+a][dd];
      #pragma unroll
      for (int b = 0; b < 8; b++) v[b] = Vt[dd][tk*8+b];
      #pragma unroll
      for (int a = 0; a < 4; a++)
        #pragma unroll
        for (int b = 0; b < 8; b++) acc[a][b] += g[a]*v[b];
    }
    __syncthreads();
  }
  for (int a = 0; a < 4; a++)
    for (int b = 0; b < 8; b++)
      atomicAdd(&P[(size_t)(m0 + tm*4 + a)*64 + tk*8 + b], acc[a][b]);
}

// ---------------- W += G^T @ U   grid(32,16) ----------------
__global__ void k_gtu(float* __restrict__ W, const float* __restrict__ G,
                      const float* __restrict__ U){
  __shared__ float Gt[32][129];
  __shared__ float Ut[32][65];
  int d0 = blockIdx.x * 128, m0 = blockIdx.y * 512;
  int t = threadIdx.x;
  int tg = t >> 4, tk = t & 15;
  float acc[8][4] = {};
  for (int mc = 0; mc < 512; mc += 32){
    for (int i = 0; i < 16; i++){
      int idx = i*256 + t; int r = idx >> 7, c = idx & 127;
      Gt[r][c] = G[(size_t)(m0+mc+r)*4096 + d0 + c];
    }
    for (int i = 0; i < 8; i++){
      int idx = i*256 + t; int r = idx >> 6, c = idx & 63;
      Ut[r][c] = U[(size_t)(m0+mc+r)*64 + c];
    }
    __syncthreads();
    for (int mm = 0; mm < 32; mm++){
      float g[8], u[4];
      #pragma unroll
      for (int a = 0; a < 8; a++) g[a] = Gt[mm][tg*8+a];
      #pragma unroll
      for (int b = 0; b < 4; b++) u[b] = Ut[mm][tk*4+b];
      #pragma unroll
      for (int a = 0; a < 8; a++)
        #pragma unroll
        for (int b = 0; b < 4; b++) acc[a][b] += g[a]*u[b];
    }
    __syncthreads();
  }
  for (int a = 0; a < 8; a++)
    for (int b = 0; b < 4; b++)
      atomicAdd(&W[(size_t)(d0 + tg*8 + a)*64 + tk*4 + b], acc[a][b]);
}

// ---------------- Gram += Pchunk^T Pchunk   grid 64 ----------------
__global__ void k_gram(const float* __restrict__ P, float* __restrict__ Gram){
  __shared__ float Pt[128][65];
  int m0 = blockIdx.x * 128;
  int t = threadIdx.x;
  for (int i = 0; i < 32; i++){
    int idx = i*256 + t; int r = idx >> 6, c = idx & 63;
    Pt[r][c] = P[(size_t)(m0+r)*64 + c];
  }
  __syncthreads();
  int ti = t >> 4, tj = t & 15;
  float acc[4][4] = {};
  for (int r = 0; r < 128; r++){
    float a[4], b[4];
    #pragma unroll
    for (int q = 0; q < 4; q++) a[q] = Pt[r][ti*4+q];
    #pragma unroll
    for (int q = 0; q < 4; q++) b[q] = Pt[r][tj*4+q];
    #pragma unroll
    for (int x = 0; x < 4; x++)
      #pragma unroll
      for (int y = 0; y < 4; y++) acc[x][y] += a[x]*b[y];
  }
  for (int x = 0; x < 4; x++)
    for (int y = 0; y < 4; y++)
      atomicAdd(&Gram[(ti*4+x)*64 + tj*4+y], acc[x][y]);
}

// ---------------- Cholesky (fp64) of 64x64 Gram + lower-tri inverse, 1 block x 64 ----------------
__global__ void k_cholinv(const float* __restrict__ Gram, float* __restrict__ Linv){
  __shared__ double A[64][64];
  __shared__ double Li[64][64];
  int t = threadIdx.x;
  for (int j = 0; j < 64; j++){ A[t][j] = (double)Gram[t*64+j]; Li[t][j] = 0.0; }
  __syncthreads();
  for (int k = 0; k < 64; k++){
    if (t == k) A[k][k] = sqrt(A[k][k]);
    __syncthreads();
    if (t > k) A[t][k] /= A[k][k];
    __syncthreads();
    if (t > k){
      double aik = A[t][k];
      for (int j = k+1; j <= t; j++) A[t][j] -= aik * A[j][k];
    }
    __syncthreads();
  }
  // invert L; thread t owns column t (independent forward substitution)
  for (int i = t; i < 64; i++){
    double s = (i == t) ? 1.0 : 0.0;
    for (int p = t; p < i; p++) s -= A[i][p] * Li[p][t];
    Li[i][t] = s / A[i][i];
  }
  __syncthreads();
  for (int j = 0; j < 64; j++) Linv[t*64+j] = (float)Li[t][j];
}

// ---------------- U = P @ Linv^T   grid 128 ----------------
__global__ void k_applyq(float* __restrict__ U, const float* __restrict__ P,
                         const float* __restrict__ Linv){
  __shared__ float Pt[64][65];
  __shared__ float Lt[64][65];
  int m0 = blockIdx.x * 64;
  int t = threadIdx.x;
  for (int i = 0; i < 16; i++){
    int idx = i*256 + t; int r = idx >> 6, c = idx & 63;
    Pt[r][c] = P[(size_t)(m0+r)*64 + c];
    Lt[r][c] = Linv[r*64 + c];
  }
  __syncthreads();
  int tm = t >> 4, tj = t & 15;
  float acc[4][4] = {};
  for (int i = 0; i < 64; i++){
    float p[4], lv[4];
    #pragma unroll
    for (int a = 0; a < 4; a++) p[a]  = Pt[tm*4+a][i];
    #pragma unroll
    for (int b = 0; b < 4; b++) lv[b] = Lt[tj*4+b][i];
    #pragma unroll
    for (int a = 0; a < 4; a++)
      #pragma unroll
      for (int b = 0; b < 4; b++) acc[a][b] += p[a]*lv[b];
  }
  for (int a = 0; a < 4; a++)
    for (int b = 0; b < 4; b++)
      U[(size_t)(m0+tm*4+a)*64 + tj*4+b] = acc[a][b];
}

// ---------------- column norms of W[4096,64]  grid 64 ----------------
__global__ void k_colnorm(const float* __restrict__ W, float* __restrict__ cn){
  int k = blockIdx.x;
  float s = 0.f;
  for (int d = threadIdx.x; d < 4096; d += 256){
    float v = W[(size_t)d*64 + k];
    s += v*v;
  }
  for (int o = 32; o > 0; o >>= 1) s += __shfl_down(s, o, 64);
  __shared__ float sm[4];
  int lane = threadIdx.x & 63, w = threadIdx.x >> 6;
  if (lane == 0) sm[w] = s;
  __syncthreads();
  if (threadIdx.x == 0) cn[k] = sqrtf(sm[0]+sm[1]+sm[2]+sm[3]);
}

// ---------------- V = W / (norm+EPS)  grid 1024 ----------------
__global__ void k_vnorm(float* __restrict__ V, const float* __restrict__ W,
                        const float* __restrict__ cn){
  int i = blockIdx.x*256 + threadIdx.x;
  int k = i & 63;
  V[i] = W[i] / (cn[k] + EPSF);
}

// ---------------- Vn = W/(S+EPS), KV[k][d] = S*Vn, amax_v  grid 1024 ----------------
__global__ void k_vnkv(float* __restrict__ V, float* __restrict__ KV,
                       const float* __restrict__ W, const float* __restrict__ S,
                       unsigned* __restrict__ amaxv){
  int i = blockIdx.x*256 + threadIdx.x;
  int k = i & 63, d = i >> 6;
  float s = S[k];
  float vn = W[i] / (s + EPSF);
  V[i] = vn;
  KV[(size_t)k*4096 + d] = s * vn;
  float m = fabsf(vn);
  for (int o = 32; o > 0; o >>= 1) m = fmaxf(m, __shfl_down(m, o, 64));
  __shared__ float sm[4];
  int lane = threadIdx.x & 63, w = threadIdx.x >> 6;
  if (lane == 0) sm[w] = m;
  __syncthreads();
  if (threadIdx.x == 0)
    atomicMax(amaxv, __float_as_uint(fmaxf(fmaxf(sm[0],sm[1]), fmaxf(sm[2],sm[3]))));
}

// ---------------- quantize weight -> Bq[:, :4096]  grid 65536 ----------------
__global__ void k_qw(__bf16* __restrict__ Bq, const float* __restrict__ w,
                     const unsigned* __restrict__ amaxw){
  float s = fmaxf(__uint_as_float(*amaxw) / 6.0f, EPSF);
  int i = blockIdx.x*256 + threadIdx.x;
  if (i >= 16777216) return;
  int n = i >> 12, d = i & 4095;
  Bq[(size_t)n*4160 + d] = (__bf16)qgrid(w[i], s);
}

// ---------------- quantize U -> Aq[:, 4096:4160]  grid 2048 ----------------
__global__ void k_qu(__bf16* __restrict__ Aq, const float* __restrict__ U,
                     const unsigned* __restrict__ amaxu){
  float s = fmaxf(__uint_as_float(*amaxu) / 6.0f, EPSF);
  int i = blockIdx.x*256 + threadIdx.x;
  int m = i >> 6, k = i & 63;
  Aq[(size_t)m*4160 + 4096 + k] = (__bf16)qgrid(U[i], s);
}

// ---------------- quantize V -> Vq[k][d] grid  grid 1024 ----------------
__global__ void k_qv(__bf16* __restrict__ Vq, const float* __restrict__ V,
                     const unsigned* __restrict__ amaxv){
  float s = fmaxf(__uint_as_float(*amaxv) / 6.0f, EPSF);
  int i = blockIdx.x*256 + threadIdx.x;
  int k = i & 63, d = i >> 6;
  Vq[(size_t)k*4096 + d] = (__bf16)qgrid(V[i], s);
}

// ---------------- residual: ker = U @ KV; res = x - ker; amax (mode 0) or quantize->Aq (mode 1)
// grid (128, 32), tile 64m x 128n
__global__ void k_res(const float* __restrict__ x, const float* __restrict__ U,
                      const float* __restrict__ KV, unsigned* __restrict__ amaxr,
                      __bf16* __restrict__ Aq, int mode){
  __shared__ float Ut[64][65];
  __shared__ float KVt[64][128];
  int m0 = blockIdx.x * 64, n0 = blockIdx.y * 128;
  int t = threadIdx.x;
  for (int i = 0; i < 16; i++){
    int idx = i*256 + t; int r = idx >> 6, c = idx & 63;
    Ut[r][c] = U[(size_t)(m0+r)*64 + c];
  }
  for (int i = 0; i < 32; i++){
    int idx = i*256 + t; int r = idx >> 7, c = idx & 127;
    KVt[r][c] = KV[(size_t)r*4096 + n0 + c];
  }
  __syncthreads();
  int tm = t >> 5, tn = t & 31;
  float acc[8][4] = {};
  for (int k = 0; k < 64; k++){
    float4 kv = *(const float4*)&KVt[k][tn*4];
    #pragma unroll
    for (int a = 0; a < 8; a++){
      float uu = Ut[tm*8+a][k];
      acc[a][0] += uu*kv.x; acc[a][1] += uu*kv.y;
      acc[a][2] += uu*kv.z; acc[a][3] += uu*kv.w;
    }
  }
  if (mode == 0){
    float mx = 0.f;
    for (int a = 0; a < 8; a++){
      float4 xv = *(const float4*)&x[(size_t)(m0+tm*8+a)*4096 + n0 + tn*4];
      mx = fmaxf(mx, fabsf(xv.x - acc[a][0]));
      mx = fmaxf(mx, fabsf(xv.y - acc[a][1]));
      mx = fmaxf(mx, fabsf(xv.z - acc[a][2]));
      mx = fmaxf(mx, fabsf(xv.w - acc[a][3]));
    }
    for (int o = 32; o > 0; o >>= 1) mx = fmaxf(mx, __shfl_down(mx, o, 64));
    __shared__ float sm[4];
    int lane = t & 63, w = t >> 6;
    if (lane == 0) sm[w] = mx;
    __syncthreads();
    if (t == 0)
      atomicMax(amaxr, __float_as_uint(fmaxf(fmaxf(sm[0],sm[1]), fmaxf(sm[2],sm[3]))));
  } else {
    float s = fmaxf(__uint_as_float(*amaxr)/6.0f, EPSF);
    for (int a = 0; a < 8; a++){
      float4 xv = *(const float4*)&x[(size_t)(m0+tm*8+a)*4096 + n0 + tn*4];
      size_t o = (size_t)(m0+tm*8+a)*4160 + n0 + tn*4;
      Aq[o+0] = (__bf16)qgrid(xv.x - acc[a][0], s);
      Aq[o+1] = (__bf16)qgrid(xv.y - acc[a][1], s);
      Aq[o+2] = (__bf16)qgrid(xv.z - acc[a][2], s);
      Aq[o+3] = (__bf16)qgrid(xv.w - acc[a][3], s);
    }
  }
}

// ---------------- M1 += Vq @ Wq^T   ([64,4096] x [4096,4096]^T) grid (64,8) ----------------
__global__ void k_m1(float* __restrict__ M1g, const __bf16* __restrict__ Vq,
                     const __bf16* __restrict__ Bq){
  __shared__ float Vt[64][65];
  __shared__ float Wt[64][65];
  int n0 = blockIdx.x * 64, d0 = blockIdx.y * 512;
  int t = threadIdx.x;
  int tk = t >> 4, tn = t & 15;
  float acc[4][4] = {};
  for (int dc = 0; dc < 512; dc += 64){
    for (int i = 0; i < 16; i++){
      int idx = i*256 + t; int r = idx >> 6, c = idx & 63;
      Vt[c][r] = (float)Vq[(size_t)r*4096 + d0 + dc + c];
      Wt[c][r] = (float)Bq[(size_t)(n0 + r)*4160 + d0 + dc + c];
    }
    __syncthreads();
    for (int dd = 0; dd < 64; dd++){
      float v[4], wv[4];
      #pragma unroll
      for (int a = 0; a < 4; a++) v[a]  = Vt[dd][tk*4+a];
      #pragma unroll
      for (int b = 0; b < 4; b++) wv[b] = Wt[dd][tn*4+b];
      #pragma unroll
      for (int a = 0; a < 4; a++)
        #pragma unroll
        for (int b = 0; b < 4; b++) acc[a][b] += v[a]*wv[b];
    }
    __syncthreads();
  }
  for (int a = 0; a < 4; a++)
    for (int b = 0; b < 4; b++)
      atomicAdd(&M1g[(size_t)(tk*4+a)*4096 + n0 + tn*4 + b], acc[a][b]);
}

// ---------------- M2T: Bq[:, 4096:4160] = M1[k][n] * su*sv*S[k]/sr   grid 1024 ----------------
__global__ void k_m2t(__bf16* __restrict__ Bq, const float* __restrict__ M1g,
                      const float* __restrict__ S, const unsigned* __restrict__ scal){
  float su = fmaxf(__uint_as_float(scal[1])/6.0f, EPSF);
  float sv = fmaxf(__uint_as_float(scal[2])/6.0f, EPSF);
  float sr = fmaxf(__uint_as_float(scal[3])/6.0f, EPSF);
  int i = blockIdx.x*256 + threadIdx.x;     // [n][k]
  int n = i >> 6, k = i & 63;
  float v = M1g[(size_t)k*4096 + n] * (su * sv * S[k] / sr);
  Bq[(size_t)n*4160 + 4096 + k] = (__bf16)v;
}

// ---------------- main bf16 MFMA GEMM: out = (A @ B^T)*sr*sw + bias ----------------
// A [8192, 4160] bf16, B [4096, 4160] bf16, out [8192,4096] f32. grid (32, 64), block 256.
__global__ __launch_bounds__(256)
void k_gemm(float* __restrict__ out, const __bf16* __restrict__ A,
            const __bf16* __restrict__ B, const float* __restrict__ bias,
            const unsigned* __restrict__ scal){
  __shared__ __align__(16) __bf16 As[128*64];
  __shared__ __align__(16) __bf16 Bs[128*64];
  int m0 = blockIdx.y * 128, n0 = blockIdx.x * 128;
  int t = threadIdx.x;
  int lane = t & 63;
  int wave = t >> 6;
  int wrow = wave & 1, wcol = wave >> 1;
  f32x4 acc[4][4] = {};

  for (int kt = 0; kt < KT; kt += 64){
    #pragma unroll
    for (int i = 0; i < 4; i++){
      int idx = i*256 + t;
      int r = idx >> 3, slot = idx & 7;
      int c = slot ^ (r & 7);
      const __bf16* ga = A + (size_t)(m0 + r)*KT + kt + c*8;
      const __bf16* gb = B + (size_t)(n0 + r)*KT + kt + c*8;
      __bf16* la = As + (size_t)(i*256 + (t & ~63))*8;   // wave-uniform base; HW adds lane*16B
      __bf16* lb = Bs + (size_t)(i*256 + (t & ~63))*8;
      __builtin_amdgcn_global_load_lds((const __attribute__((address_space(1))) uint32_t*)ga,
                                       (__attribute__((address_space(3))) uint32_t*)la, 16, 0, 0);
      __builtin_amdgcn_global_load_lds((const __attribute__((address_space(1))) uint32_t*)gb,
                                       (__attribute__((address_space(3))) uint32_t*)lb, 16, 0, 0);
    }
    __syncthreads();
    #pragma unroll
    for (int ks = 0; ks < 2; ks++){
      bf16x8 fa[4], fb[4];
      int c = ks*4 + (lane >> 4);
      #pragma unroll
      for (int f = 0; f < 4; f++){
        int row = wrow*64 + f*16 + (lane & 15);
        fa[f] = *(const bf16x8*)(As + ((size_t)row*8 + (c ^ (row & 7)))*8);
        int col = wcol*64 + f*16 + (lane & 15);
        fb[f] = *(const bf16x8*)(Bs + ((size_t)col*8 + (c ^ (col & 7)))*8);
      }
      #pragma unroll
      for (int fm = 0; fm < 4; fm++)
        #pragma unroll
        for (int fn = 0; fn < 4; fn++)
          acc[fm][fn] = __builtin_amdgcn_mfma_f32_16x16x32_bf16(fa[fm], fb[fn], acc[fm][fn], 0, 0, 0);
    }
    __syncthreads();
  }

  float sr = fmaxf(__uint_as_float(scal[3])/6.0f, EPSF);
  float sw = fmaxf(__uint_as_float(scal[0])/6.0f, EPSF);
  float srw = sr * sw;
  #pragma unroll
  for (int fn = 0; fn < 4; fn++){
    int n = n0 + wcol*64 + fn*16 + (lane & 15);
    float bs = bias[n];
    #pragma unroll
    for (int fm = 0; fm < 4; fm++){
      int mb = m0 + wrow*64 + fm*16 + 4*(lane >> 4);
      #pragma unroll
      for (int r = 0; r < 4; r++)
        out[(size_t)(mb + r)*4096 + n] = acc[fm][fn][r] * srw + bs;
    }
  }
}

// ---------------- host side ----------------
extern "C" void kernel_launch(void* const* d_in, const int* in_sizes, int n_in,
                              void* d_out, int out_size, void* d_ws, size_t ws_size,
                              hipStream_t stream){
  const float* x    = (const float*)d_in[0];   // [8192, 4096]
  const float* wt   = (const float*)d_in[1];   // [4096, 4096]
  const float* bias = (const float*)d_in[2];   // [4096]
  const float* V0   = (const float*)d_in[3];   // [4096, 64]
  float* out = (float*)d_out;
  if (ws_size < WS_NEED) return;               // would corrupt; fail visibly instead

  float* F = (float*)d_ws;
  unsigned* scal = (unsigned*)(F + oScal);
  __bf16* BFp = (__bf16*)((char*)d_ws + bfByte);
  __bf16* Vq = BFp + oVq;
  __bf16* Aq = BFp + oA;
  __bf16* Bq = BFp + oB;
  float *P = F+oP, *W = F+oW, *Gm = F+oG, *M1 = F+oM1, *Sv = F+oS,
        *Li = F+oLinv, *V = F+oV, *KV = F+oKV, *Ub = F+oU;

  dim3 b256(256);
  k_zero<<<dim3(2048), b256, 0, stream>>>(F, (int)nZero1);
  k_amax<<<dim3(2048), b256, 0, stream>>>(wt, 16777216, scal+0);
  k_qw  <<<dim3(65536), b256, 0, stream>>>(Bq, wt, scal+0);

  // power iteration 1
  k_gv     <<<dim3(64,8),  b256, 0, stream>>>(P, x, V0);
  k_gram   <<<dim3(64),    b256, 0, stream>>>(P, Gm);
  k_cholinv<<<dim3(1), dim3(64), 0, stream>>>(Gm, Li);
  k_applyq <<<dim3(128),   b256, 0, stream>>>(Ub, P, Li);
  k_zero   <<<dim3(1024),  b256, 0, stream>>>(P, 8192*64);
  k_zero   <<<dim3(16),    b256, 0, stream>>>(Gm, 64*64);
  k_gtu    <<<dim3(32,16), b256, 0, stream>>>(W, x, Ub);
  k_colnorm<<<dim3(64),    b256, 0, stream>>>(W, Sv);
  k_vnorm  <<<dim3(1024),  b256, 0, stream>>>(V, W, Sv);
  k_zero   <<<dim3(512),   b256, 0, stream>>>(W, 4096*64);

  // power iteration 2
  k_gv     <<<dim3(64,8),  b256, 0, stream>>>(P, x, V);
  k_gram   <<<dim3(64),    b256, 0, stream>>>(P, Gm);
  k_cholinv<<<dim3(1), dim3(64), 0, stream>>>(Gm, Li);
  k_applyq <<<dim3(128),   b256, 0, stream>>>(Ub, P, Li);
  k_gtu    <<<dim3(32,16), b256, 0, stream>>>(W, x, Ub);
  k_colnorm<<<dim3(64),    b256, 0, stream>>>(W, Sv);       // Sv = S
  k_vnkv   <<<dim3(1024),  b256, 0, stream>>>(V, KV, W, Sv, scal+2);

  // quantize factors + residual
  k_amax<<<dim3(2048), b256, 0, stream>>>(Ub, 8192*64, scal+1);
  k_qu  <<<dim3(2048), b256, 0, stream>>>(Aq, Ub, scal+1);
  k_qv  <<<dim3(1024), b256, 0, stream>>>(Vq, V, scal+2);
  k_res <<<dim3(128,32), b256, 0, stream>>>(x, Ub, KV, scal+3, Aq, 0);
  k_res <<<dim3(128,32), b256, 0, stream>>>(x, Ub, KV, scal+3, Aq, 1);

  // low-rank factor fold + main GEMM
  k_m1  <<<dim3(64,8), b256, 0, stream>>>(M1, Vq, Bq);
  k_m2t <<<dim3(1024), b256, 0, stream>>>(Bq, M1, Sv, scal);
  k_gemm<<<dim3(32,64), b256, 0, stream>>>(out, Aq, Bq, bias, scal);
}

// Round 2
// 1630.525 us; speedup vs baseline: 1.3297x; 1.3297x over previous
//
#include <hip/hip_runtime.h>
#include <stdint.h>

#define EPSF 1e-8f
#define KT 4160

typedef float  f32x4  __attribute__((ext_vector_type(4)));
typedef __bf16 bf16x8 __attribute__((ext_vector_type(8)));
typedef __bf16 bf16x4 __attribute__((ext_vector_type(4)));

// ---------------- workspace layout ----------------
// fp32 region (element offsets)
constexpr size_t oP    = 0;                     // P   [8192*64]
constexpr size_t oW    = oP  + 8192*64;         // W   [4096*64]
constexpr size_t oG    = oW  + 4096*64;         // Gram[64*64]
constexpr size_t oM1   = oG  + 64*64;           // M1  [64*4096]
constexpr size_t oScal = oM1 + 64*4096;         // 4 u32: amax_w, amax_u, amax_v, amax_r
constexpr size_t nZero1= oScal + 4;             // initial zero: P,W,G,M1,scal
constexpr size_t nZero2= oG + 64*64;            // iter-2 zero: P,W,G
constexpr size_t oS    = nZero1;                // 64
constexpr size_t oLinv = oS + 64;               // 64*64
constexpr size_t oV    = oLinv + 64*64;         // V  [4096*64]
constexpr size_t oU    = oV + 4096*64;          // Ub [8192*64]
constexpr size_t endF32= oU + 8192*64;
constexpr size_t bfByte= ((endF32*4 + 255)/256)*256;
// bf16 region (element offsets)
constexpr size_t oVq   = 0;                     // Vq [64*4096]
constexpr size_t oA    = oVq + 64*4096;         // A = [Rq | Uq]  [8192*4160]
constexpr size_t oB    = oA + (size_t)8192*4160;// B = [Wq | M2T] [4096*4160]
constexpr size_t oVcT  = oB + (size_t)4096*4160;// VcT h/m/l 3x[64*4096]
constexpr size_t oUT   = oVcT + 3*(size_t)64*4096;   // UT h/m/l 3x[64*8192]
constexpr size_t oUhl  = oUT + 3*(size_t)64*8192;    // U h/l 2x[8192*64]
constexpr size_t oKVT  = oUhl + 2*(size_t)8192*64;   // KVT h/l 2x[4096*64]
constexpr size_t endBF = oKVT + 2*(size_t)4096*64;
constexpr size_t WS_NEED = bfByte + endBF*2;

// ---------------- fp4 e2m1 helpers ----------------
__device__ __forceinline__ float qlevel(float a){
  if (a <= 0.25f) return 0.0f;
  if (a <= 0.75f) return 0.5f;
  if (a <= 1.25f) return 1.0f;
  if (a <= 1.75f) return 1.5f;
  if (a <= 2.5f)  return 2.0f;
  if (a <= 3.5f)  return 3.0f;
  if (a <= 5.0f)  return 4.0f;
  return 6.0f;
}
__device__ __forceinline__ float qgrid(float v, float s){
  float y = v / s;
  float l = qlevel(fabsf(y));
  return y < 0.0f ? -l : l;
}

// ---------------- utility ----------------
__global__ void k_zero(float* p, int n){
  for (int i = blockIdx.x*blockDim.x + threadIdx.x; i < n; i += gridDim.x*blockDim.x)
    p[i] = 0.0f;
}

__global__ void k_amax4(const float4* __restrict__ x, int n4, unsigned* __restrict__ out){
  float m = 0.f;
  for (int i = blockIdx.x*blockDim.x + threadIdx.x; i < n4; i += gridDim.x*blockDim.x){
    float4 v = x[i];
    m = fmaxf(m, fmaxf(fmaxf(fabsf(v.x), fabsf(v.y)), fmaxf(fabsf(v.z), fabsf(v.w))));
  }
  for (int o = 32; o > 0; o >>= 1) m = fmaxf(m, __shfl_down(m, o, 64));
  __shared__ float sm[4];
  int lane = threadIdx.x & 63, w = threadIdx.x >> 6;
  if (lane == 0) sm[w] = m;
  __syncthreads();
  if (threadIdx.x == 0)
    atomicMax(out, __float_as_uint(fmaxf(fmaxf(sm[0],sm[1]), fmaxf(sm[2],sm[3]))));
}

// ---------------- P += x @ Vc  via 3-word-split bf16 MFMA  grid(64,8) ----------------
// A-frags register-assembled from fp32 x; B = VcT h/m/l [64,4096] bf16.
__global__ __launch_bounds__(256) void k_gv(
    float* __restrict__ P, const float* __restrict__ x,
    const __bf16* __restrict__ Bh, const __bf16* __restrict__ Bm, const __bf16* __restrict__ Bl){
  int m0 = blockIdx.x * 128;
  int d0 = blockIdx.y * 512;
  int lane = threadIdx.x & 63, wave = threadIdx.x >> 6;
  int kgrp = lane >> 4, lrow = lane & 15;
  f32x4 acc[2][4] = {};
  for (int dc = d0; dc < d0 + 512; dc += 32){
    bf16x8 ah[2], am[2], al[2];
    #pragma unroll
    for (int f = 0; f < 2; f++){
      const float* g = x + (size_t)(m0 + wave*32 + f*16 + lrow)*4096 + dc + kgrp*8;
      float4 a = *(const float4*)g;
      float4 b = *(const float4*)(g + 4);
      float v[8] = {a.x,a.y,a.z,a.w,b.x,b.y,b.z,b.w};
      #pragma unroll
      for (int j = 0; j < 8; j++){
        __bf16 h = (__bf16)v[j];
        float r1 = v[j] - (float)h;
        __bf16 md = (__bf16)r1;
        float r2 = r1 - (float)md;
        ah[f][j] = h; am[f][j] = md; al[f][j] = (__bf16)r2;
      }
    }
    #pragma unroll
    for (int n = 0; n < 4; n++){
      size_t bo = (size_t)(n*16 + lrow)*4096 + dc + kgrp*8;
      bf16x8 bh = *(const bf16x8*)(Bh + bo);
      bf16x8 bm = *(const bf16x8*)(Bm + bo);
      bf16x8 bl = *(const bf16x8*)(Bl + bo);
      #pragma unroll
      for (int f = 0; f < 2; f++){
        acc[f][n] = __builtin_amdgcn_mfma_f32_16x16x32_bf16(ah[f], bh, acc[f][n],0,0,0);
        acc[f][n] = __builtin_amdgcn_mfma_f32_16x16x32_bf16(ah[f], bm, acc[f][n],0,0,0);
        acc[f][n] = __builtin_amdgcn_mfma_f32_16x16x32_bf16(am[f], bh, acc[f][n],0,0,0);
        acc[f][n] = __builtin_amdgcn_mfma_f32_16x16x32_bf16(ah[f], bl, acc[f][n],0,0,0);
        acc[f][n] = __builtin_amdgcn_mfma_f32_16x16x32_bf16(al[f], bh, acc[f][n],0,0,0);
        acc[f][n] = __builtin_amdgcn_mfma_f32_16x16x32_bf16(am[f], bm, acc[f][n],0,0,0);
      }
    }
  }
  #pragma unroll
  for (int f = 0; f < 2; f++)
    #pragma unroll
    for (int n = 0; n < 4; n++)
      #pragma unroll
      for (int r = 0; r < 4; r++)
        atomicAdd(&P[(size_t)(m0 + wave*32 + f*16 + kgrp*4 + r)*64 + n*16 + lrow], acc[f][n][r]);
}

// ---------------- W += x^T @ U  (transposed A from fp32 x)  grid(64,8) ----------------
__global__ __launch_bounds__(256) void k_gtu(
    float* __restrict__ W, const float* __restrict__ x,
    const __bf16* __restrict__ Bh, const __bf16* __restrict__ Bm, const __bf16* __restrict__ Bl){
  int d0 = blockIdx.x * 64;
  int m0 = blockIdx.y * 1024;
  int lane = threadIdx.x & 63, wave = threadIdx.x >> 6;
  int kgrp = lane >> 4, lrow = lane & 15;
  int dcol = d0 + wave*16 + lrow;
  f32x4 acc[4] = {};
  for (int mc = m0; mc < m0 + 1024; mc += 32){
    bf16x8 ah, am, al;
    int mb = mc + kgrp*8;
    #pragma unroll
    for (int j = 0; j < 8; j++){
      float v = x[(size_t)(mb + j)*4096 + dcol];
      __bf16 h = (__bf16)v;
      float r1 = v - (float)h;
      __bf16 md = (__bf16)r1;
      float r2 = r1 - (float)md;
      ah[j] = h; am[j] = md; al[j] = (__bf16)r2;
    }
    #pragma unroll
    for (int n = 0; n < 4; n++){
      size_t bo = (size_t)(n*16 + lrow)*8192 + mc + kgrp*8;
      bf16x8 bh = *(const bf16x8*)(Bh + bo);
      bf16x8 bm = *(const bf16x8*)(Bm + bo);
      bf16x8 bl = *(const bf16x8*)(Bl + bo);
      acc[n] = __builtin_amdgcn_mfma_f32_16x16x32_bf16(ah, bh, acc[n],0,0,0);
      acc[n] = __builtin_amdgcn_mfma_f32_16x16x32_bf16(ah, bm, acc[n],0,0,0);
      acc[n] = __builtin_amdgcn_mfma_f32_16x16x32_bf16(am, bh, acc[n],0,0,0);
      acc[n] = __builtin_amdgcn_mfma_f32_16x16x32_bf16(ah, bl, acc[n],0,0,0);
      acc[n] = __builtin_amdgcn_mfma_f32_16x16x32_bf16(al, bh, acc[n],0,0,0);
      acc[n] = __builtin_amdgcn_mfma_f32_16x16x32_bf16(am, bm, acc[n],0,0,0);
    }
  }
  #pragma unroll
  for (int n = 0; n < 4; n++)
    #pragma unroll
    for (int r = 0; r < 4; r++)
      atomicAdd(&W[(size_t)(d0 + wave*16 + kgrp*4 + r)*64 + n*16 + lrow], acc[n][r]);
}

// ---------------- Gram += Pchunk^T Pchunk   grid 64 ----------------
__global__ void k_gram(const float* __restrict__ P, float* __restrict__ Gram){
  __shared__ float Pt[128][65];
  int m0 = blockIdx.x * 128;
  int t = threadIdx.x;
  for (int i = 0; i < 32; i++){
    int idx = i*256 + t; int r = idx >> 6, c = idx & 63;
    Pt[r][c] = P[(size_t)(m0+r)*64 + c];
  }
  __syncthreads();
  int ti = t >> 4, tj = t & 15;
  float acc[4][4] = {};
  for (int r = 0; r < 128; r++){
    float a[4], b[4];
    #pragma unroll
    for (int q = 0; q < 4; q++) a[q] = Pt[r][ti*4+q];
    #pragma unroll
    for (int q = 0; q < 4; q++) b[q] = Pt[r][tj*4+q];
    #pragma unroll
    for (int xx = 0; xx < 4; xx++)
      #pragma unroll
      for (int y = 0; y < 4; y++) acc[xx][y] += a[xx]*b[y];
  }
  for (int xx = 0; xx < 4; xx++)
    for (int y = 0; y < 4; y++)
      atomicAdd(&Gram[(ti*4+xx)*64 + tj*4+y], acc[xx][y]);
}

// ---------------- fp64 Cholesky of Gram + lower-tri inverse ----------------
__global__ void k_cholinv(const float* __restrict__ Gram, float* __restrict__ Linv){
  __shared__ double A[64][64];
  __shared__ double Li[64][64];
  int t = threadIdx.x;
  for (int j = 0; j < 64; j++){ A[t][j] = (double)Gram[t*64+j]; Li[t][j] = 0.0; }
  __syncthreads();
  for (int k = 0; k < 64; k++){
    if (t == k) A[k][k] = sqrt(A[k][k]);
    __syncthreads();
    if (t > k) A[t][k] /= A[k][k];
    __syncthreads();
    if (t > k){
      double aik = A[t][k];
      for (int j = k+1; j <= t; j++) A[t][j] -= aik * A[j][k];
    }
    __syncthreads();
  }
  for (int i = t; i < 64; i++){
    double s = (i == t) ? 1.0 : 0.0;
    for (int p = t; p < i; p++) s -= A[i][p] * Li[p][t];
    Li[i][t] = s / A[i][i];
  }
  __syncthreads();
  for (int j = 0; j < 64; j++) Linv[t*64+j] = (float)Li[t][j];
}

// ---------------- U = P @ Linv^T   grid 128 ----------------
__global__ void k_applyq(float* __restrict__ U, const float* __restrict__ P,
                         const float* __restrict__ Linv){
  __shared__ float Pt[64][65];
  __shared__ float Lt[64][65];
  int m0 = blockIdx.x * 64;
  int t = threadIdx.x;
  for (int i = 0; i < 16; i++){
    int idx = i*256 + t; int r = idx >> 6, c = idx & 63;
    Pt[r][c] = P[(size_t)(m0+r)*64 + c];
    Lt[r][c] = Linv[r*64 + c];
  }
  __syncthreads();
  int tm = t >> 4, tj = t & 15;
  float acc[4][4] = {};
  for (int i = 0; i < 64; i++){
    float p[4], lv[4];
    #pragma unroll
    for (int a = 0; a < 4; a++) p[a]  = Pt[tm*4+a][i];
    #pragma unroll
    for (int b = 0; b < 4; b++) lv[b] = Lt[tj*4+b][i];
    #pragma unroll
    for (int a = 0; a < 4; a++)
      #pragma unroll
      for (int b = 0; b < 4; b++) acc[a][b] += p[a]*lv[b];
  }
  for (int a = 0; a < 4; a++)
    for (int b = 0; b < 4; b++)
      U[(size_t)(m0+tm*4+a)*64 + tj*4+b] = acc[a][b];
}

// ---------------- column norms of W[4096,64]  grid 64 ----------------
__global__ void k_colnorm(const float* __restrict__ W, float* __restrict__ cn){
  int k = blockIdx.x;
  float s = 0.f;
  for (int d = threadIdx.x; d < 4096; d += 256){
    float v = W[(size_t)d*64 + k];
    s += v*v;
  }
  for (int o = 32; o > 0; o >>= 1) s += __shfl_down(s, o, 64);
  __shared__ float sm[4];
  int lane = threadIdx.x & 63, w = threadIdx.x >> 6;
  if (lane == 0) sm[w] = s;
  __syncthreads();
  if (threadIdx.x == 0) cn[k] = sqrtf(sm[0]+sm[1]+sm[2]+sm[3]);
}

__global__ void k_vnorm(float* __restrict__ V, const float* __restrict__ W,
                        const float* __restrict__ cn){
  int i = blockIdx.x*256 + threadIdx.x;
  int k = i & 63;
  V[i] = W[i] / (cn[k] + EPSF);
}

// Vn = W/(S+EPS); KVT[d][k] = S*Vn (bf16 h/l); amax_v   grid 1024
__global__ void k_vnkv(float* __restrict__ V, __bf16* __restrict__ Kh, __bf16* __restrict__ Kl,
                       const float* __restrict__ W, const float* __restrict__ S,
                       unsigned* __restrict__ amaxv){
  int i = blockIdx.x*256 + threadIdx.x;
  int k = i & 63, d = i >> 6;
  float s = S[k];
  float vn = W[i] / (s + EPSF);
  V[i] = vn;
  float kv = s * vn;
  __bf16 h = (__bf16)kv;
  Kh[(size_t)d*64 + k] = h;
  Kl[(size_t)d*64 + k] = (__bf16)(kv - (float)h);
  float m = fabsf(vn);
  for (int o = 32; o > 0; o >>= 1) m = fmaxf(m, __shfl_down(m, o, 64));
  __shared__ float sm[4];
  int lane = threadIdx.x & 63, w = threadIdx.x >> 6;
  if (lane == 0) sm[w] = m;
  __syncthreads();
  if (threadIdx.x == 0)
    atomicMax(amaxv, __float_as_uint(fmaxf(fmaxf(sm[0],sm[1]), fmaxf(sm[2],sm[3]))));
}

// ---------------- transpose+3-split prep: Vc[4096,64] -> VcT h/m/l [64,4096]  grid 64 ----------------
__global__ void k_prep_vct(const float* __restrict__ Vc, __bf16* __restrict__ Th,
                           __bf16* __restrict__ Tm, __bf16* __restrict__ Tl){
  __shared__ float Vt[64][65];
  int d0 = blockIdx.x * 64;
  int t = threadIdx.x;
  for (int i = 0; i < 16; i++){
    int idx = i*256 + t; int r = idx >> 6, c = idx & 63;
    Vt[r][c] = Vc[(size_t)(d0 + r)*64 + c];
  }
  __syncthreads();
  for (int i = 0; i < 16; i++){
    int idx = i*256 + t; int k = idx >> 6, dd = idx & 63;
    float v = Vt[dd][k];
    __bf16 h = (__bf16)v;
    float r1 = v - (float)h;
    __bf16 md = (__bf16)r1;
    float r2 = r1 - (float)md;
    size_t o = (size_t)k*4096 + d0 + dd;
    Th[o] = h; Tm[o] = md; Tl[o] = (__bf16)r2;
  }
}

// prep U: Ub[8192,64] -> U h/l [8192,64] + UT h/m/l [64,8192]   grid 128
__global__ void k_prep_u(const float* __restrict__ Ub, __bf16* __restrict__ Uh, __bf16* __restrict__ Ul,
                         __bf16* __restrict__ Th, __bf16* __restrict__ Tm, __bf16* __restrict__ Tl){
  __shared__ float Ut[64][65];
  int m0 = blockIdx.x * 64;
  int t = threadIdx.x;
  for (int i = 0; i < 16; i++){
    int idx = i*256 + t; int r = idx >> 6, c = idx & 63;
    float v = Ub[(size_t)(m0 + r)*64 + c];
    Ut[r][c] = v;
    __bf16 h = (__bf16)v;
    Uh[(size_t)(m0+r)*64 + c] = h;
    Ul[(size_t)(m0+r)*64 + c] = (__bf16)(v - (float)h);
  }
  __syncthreads();
  for (int i = 0; i < 16; i++){
    int idx = i*256 + t; int k = idx >> 6, mm = idx & 63;
    float v = Ut[mm][k];
    __bf16 h = (__bf16)v;
    float r1 = v - (float)h;
    __bf16 md = (__bf16)r1;
    float r2 = r1 - (float)md;
    size_t o = (size_t)k*8192 + m0 + mm;
    Th[o] = h; Tm[o] = md; Tl[o] = (__bf16)r2;
  }
}

// ---------------- quantize weight -> Bq[:, :4096]  (float4)  grid 16384 ----------------
__global__ void k_qw(__bf16* __restrict__ Bq, const float* __restrict__ w,
                     const unsigned* __restrict__ amaxw){
  float s = fmaxf(__uint_as_float(*amaxw) / 6.0f, EPSF);
  int i = blockIdx.x*256 + threadIdx.x;          // 4.19M groups of 4
  int n = i >> 10, d = (i & 1023)*4;
  float4 v = *(const float4*)(w + (size_t)n*4096 + d);
  bf16x4 o;
  o[0] = (__bf16)qgrid(v.x, s); o[1] = (__bf16)qgrid(v.y, s);
  o[2] = (__bf16)qgrid(v.z, s); o[3] = (__bf16)qgrid(v.w, s);
  *(bf16x4*)(Bq + (size_t)n*4160 + d) = o;
}

// ---------------- quantize U -> Aq[:, 4096:4160]  grid 2048 ----------------
__global__ void k_qu(__bf16* __restrict__ Aq, const float* __restrict__ U,
                     const unsigned* __restrict__ amaxu){
  float s = fmaxf(__uint_as_float(*amaxu) / 6.0f, EPSF);
  int i = blockIdx.x*256 + threadIdx.x;
  int m = i >> 6, k = i & 63;
  Aq[(size_t)m*4160 + 4096 + k] = (__bf16)qgrid(U[i], s);
}

// ---------------- quantize V -> Vq[k][d] (LDS transpose)  grid 64 ----------------
__global__ void k_qv(__bf16* __restrict__ Vq, const float* __restrict__ V,
                     const unsigned* __restrict__ amaxv){
  __shared__ float Vt[64][65];
  float s = fmaxf(__uint_as_float(*amaxv)/6.0f, EPSF);
  int d0 = blockIdx.x * 64;
  int t = threadIdx.x;
  for (int i = 0; i < 16; i++){
    int idx = i*256 + t; int r = idx >> 6, c = idx & 63;
    Vt[r][c] = V[(size_t)(d0 + r)*64 + c];
  }
  __syncthreads();
  for (int i = 0; i < 16; i++){
    int idx = i*256 + t; int k = idx >> 6, dd = idx & 63;
    Vq[(size_t)k*4096 + d0 + dd] = (__bf16)qgrid(Vt[dd][k], s);
  }
}

// ---------------- residual: ker = U@KV via 2-split MFMA; amax or quantize  grid(128,32) ----------------
__global__ __launch_bounds__(256) void k_res(
    const float* __restrict__ x, const __bf16* __restrict__ Uh, const __bf16* __restrict__ Ul,
    const __bf16* __restrict__ Kh, const __bf16* __restrict__ Kl,
    unsigned* __restrict__ amaxr, __bf16* __restrict__ Aq, int mode){
  int m0 = blockIdx.x * 64, n0 = blockIdx.y * 128;
  int lane = threadIdx.x & 63, wave = threadIdx.x >> 6;
  int kgrp = lane >> 4, lrow = lane & 15;
  int mrow = m0 + wave*16 + lrow;
  f32x4 acc[8] = {};
  #pragma unroll
  for (int ks = 0; ks < 2; ks++){
    size_t ao = (size_t)mrow*64 + ks*32 + kgrp*8;
    bf16x8 uh = *(const bf16x8*)(Uh + ao);
    bf16x8 ul = *(const bf16x8*)(Ul + ao);
    #pragma unroll
    for (int n = 0; n < 8; n++){
      size_t bo = (size_t)(n0 + n*16 + lrow)*64 + ks*32 + kgrp*8;
      bf16x8 kh = *(const bf16x8*)(Kh + bo);
      bf16x8 kl = *(const bf16x8*)(Kl + bo);
      acc[n] = __builtin_amdgcn_mfma_f32_16x16x32_bf16(uh, kh, acc[n],0,0,0);
      acc[n] = __builtin_amdgcn_mfma_f32_16x16x32_bf16(uh, kl, acc[n],0,0,0);
      acc[n] = __builtin_amdgcn_mfma_f32_16x16x32_bf16(ul, kh, acc[n],0,0,0);
    }
  }
  int mb = m0 + wave*16 + kgrp*4;
  if (mode == 0){
    float mx = 0.f;
    #pragma unroll
    for (int n = 0; n < 8; n++){
      int c = n0 + n*16 + lrow;
      #pragma unroll
      for (int r = 0; r < 4; r++)
        mx = fmaxf(mx, fabsf(x[(size_t)(mb + r)*4096 + c] - acc[n][r]));
    }
    for (int o = 32; o > 0; o >>= 1) mx = fmaxf(mx, __shfl_down(mx, o, 64));
    __shared__ float sm[4];
    if (lane == 0) sm[wave] = mx;
    __syncthreads();
    if (threadIdx.x == 0)
      atomicMax(amaxr, __float_as_uint(fmaxf(fmaxf(sm[0],sm[1]), fmaxf(sm[2],sm[3]))));
  } else {
    float s = fmaxf(__uint_as_float(*amaxr)/6.0f, EPSF);
    #pragma unroll
    for (int n = 0; n < 8; n++){
      int c = n0 + n*16 + lrow;
      #pragma unroll
      for (int r = 0; r < 4; r++)
        Aq[(size_t)(mb + r)*4160 + c] =
          (__bf16)qgrid(x[(size_t)(mb + r)*4096 + c] - acc[n][r], s);
    }
  }
}

// ---------------- M1 += Vq @ Wq^T  (exact bf16 MFMA)  grid(64,8) ----------------
__global__ __launch_bounds__(256) void k_m1(
    float* __restrict__ M1g, const __bf16* __restrict__ Vq, const __bf16* __restrict__ Bq){
  int n0 = blockIdx.x * 64;
  int k0 = blockIdx.y * 512;
  int lane = threadIdx.x & 63, wave = threadIdx.x >> 6;
  int kgrp = lane >> 4, lrow = lane & 15;
  int nrow = n0 + wave*16 + lrow;
  f32x4 acc[4] = {};
  for (int kc = k0; kc < k0 + 512; kc += 32){
    bf16x8 fb = *(const bf16x8*)(Bq + (size_t)nrow*4160 + kc + kgrp*8);
    #pragma unroll
    for (int mt = 0; mt < 4; mt++){
      bf16x8 fa = *(const bf16x8*)(Vq + (size_t)(mt*16 + lrow)*4096 + kc + kgrp*8);
      acc[mt] = __builtin_amdgcn_mfma_f32_16x16x32_bf16(fa, fb, acc[mt],0,0,0);
    }
  }
  #pragma unroll
  for (int mt = 0; mt < 4; mt++)
    #pragma unroll
    for (int r = 0; r < 4; r++)
      atomicAdd(&M1g[(size_t)(mt*16 + kgrp*4 + r)*4096 + nrow], acc[mt][r]);
}

// ---------------- M2T: Bq[:, 4096:4160] = M1[k][n] * su*sv*S[k]/sr  grid 1024 ----------------
__global__ void k_m2t(__bf16* __restrict__ Bq, const float* __restrict__ M1g,
                      const float* __restrict__ S, const unsigned* __restrict__ scal){
  float su = fmaxf(__uint_as_float(scal[1])/6.0f, EPSF);
  float sv = fmaxf(__uint_as_float(scal[2])/6.0f, EPSF);
  float sr = fmaxf(__uint_as_float(scal[3])/6.0f, EPSF);
  int i = blockIdx.x*256 + threadIdx.x;
  int n = i >> 6, k = i & 63;
  float v = M1g[(size_t)k*4096 + n] * (su * sv * S[k] / sr);
  Bq[(size_t)n*4160 + 4096 + k] = (__bf16)v;
}

// ---------------- main bf16 MFMA GEMM: out = (A @ B^T)*sr*sw + bias ----------------
__global__ __launch_bounds__(256)
void k_gemm(float* __restrict__ out, const __bf16* __restrict__ A,
            const __bf16* __restrict__ B, const float* __restrict__ bias,
            const unsigned* __restrict__ scal){
  __shared__ __align__(16) __bf16 As[128*64];
  __shared__ __align__(16) __bf16 Bs[128*64];
  int m0 = blockIdx.y * 128, n0 = blockIdx.x * 128;
  int t = threadIdx.x;
  int lane = t & 63;
  int wave = t >> 6;
  int wrow = wave & 1, wcol = wave >> 1;
  f32x4 acc[4][4] = {};

  for (int kt = 0; kt < KT; kt += 64){
    #pragma unroll
    for (int i = 0; i < 4; i++){
      int idx = i*256 + t;
      int r = idx >> 3, slot = idx & 7;
      int c = slot ^ (r & 7);
      const __bf16* ga = A + (size_t)(m0 + r)*KT + kt + c*8;
      const __bf16* gb = B + (size_t)(n0 + r)*KT + kt + c*8;
      __bf16* la = As + (size_t)(i*256 + (t & ~63))*8;
      __bf16* lb = Bs + (size_t)(i*256 + (t & ~63))*8;
      __builtin_amdgcn_global_load_lds((const __attribute__((address_space(1))) uint32_t*)ga,
                                       (__attribute__((address_space(3))) uint32_t*)la, 16, 0, 0);
      __builtin_amdgcn_global_load_lds((const __attribute__((address_space(1))) uint32_t*)gb,
                                       (__attribute__((address_space(3))) uint32_t*)lb, 16, 0, 0);
    }
    __syncthreads();
    #pragma unroll
    for (int ks = 0; ks < 2; ks++){
      bf16x8 fa[4], fb[4];
      int c = ks*4 + (lane >> 4);
      #pragma unroll
      for (int f = 0; f < 4; f++){
        int row = wrow*64 + f*16 + (lane & 15);
        fa[f] = *(const bf16x8*)(As + ((size_t)row*8 + (c ^ (row & 7)))*8);
        int col = wcol*64 + f*16 + (lane & 15);
        fb[f] = *(const bf16x8*)(Bs + ((size_t)col*8 + (c ^ (col & 7)))*8);
      }
      #pragma unroll
      for (int fm = 0; fm < 4; fm++)
        #pragma unroll
        for (int fn = 0; fn < 4; fn++)
          acc[fm][fn] = __builtin_amdgcn_mfma_f32_16x16x32_bf16(fa[fm], fb[fn], acc[fm][fn], 0, 0, 0);
    }
    __syncthreads();
  }

  float sr = fmaxf(__uint_as_float(scal[3])/6.0f, EPSF);
  float sw = fmaxf(__uint_as_float(scal[0])/6.0f, EPSF);
  float srw = sr * sw;
  #pragma unroll
  for (int fn = 0; fn < 4; fn++){
    int n = n0 + wcol*64 + fn*16 + (lane & 15);
    float bs = bias[n];
    #pragma unroll
    for (int fm = 0; fm < 4; fm++){
      int mb = m0 + wrow*64 + fm*16 + 4*(lane >> 4);
      #pragma unroll
      for (int r = 0; r < 4; r++)
        out[(size_t)(mb + r)*4096 + n] = acc[fm][fn][r] * srw + bs;
    }
  }
}

// ---------------- host side ----------------
extern "C" void kernel_launch(void* const* d_in, const int* in_sizes, int n_in,
                              void* d_out, int out_size, void* d_ws, size_t ws_size,
                              hipStream_t stream){
  const float* x    = (const float*)d_in[0];   // [8192, 4096]
  const float* wt   = (const float*)d_in[1];   // [4096, 4096]
  const float* bias = (const float*)d_in[2];   // [4096]
  const float* V0   = (const float*)d_in[3];   // [4096, 64]
  float* out = (float*)d_out;
  if (ws_size < WS_NEED) return;

  float* F = (float*)d_ws;
  unsigned* scal = (unsigned*)(F + oScal);
  __bf16* BFp = (__bf16*)((char*)d_ws + bfByte);
  __bf16* Vq  = BFp + oVq;
  __bf16* Aq  = BFp + oA;
  __bf16* Bq  = BFp + oB;
  __bf16* VcTh = BFp + oVcT,              *VcTm = VcTh + (size_t)64*4096, *VcTl = VcTm + (size_t)64*4096;
  __bf16* UTh  = BFp + oUT,               *UTm  = UTh + (size_t)64*8192,  *UTl  = UTm + (size_t)64*8192;
  __bf16* Uh   = BFp + oUhl,              *Ul   = Uh + (size_t)8192*64;
  __bf16* KVTh = BFp + oKVT,              *KVTl = KVTh + (size_t)4096*64;
  float *P = F+oP, *W = F+oW, *Gm = F+oG, *M1 = F+oM1, *Sv = F+oS,
        *Li = F+oLinv, *V = F+oV, *Ub = F+oU;

  dim3 b256(256);
  k_zero <<<dim3(2048), b256, 0, stream>>>(F, (int)nZero1);
  k_amax4<<<dim3(1024), b256, 0, stream>>>((const float4*)wt, 4194304, scal+0);
  k_qw   <<<dim3(16384), b256, 0, stream>>>(Bq, wt, scal+0);

  // ---- power iteration 1 ----
  k_prep_vct<<<dim3(64),  b256, 0, stream>>>(V0, VcTh, VcTm, VcTl);
  k_gv     <<<dim3(64,8), b256, 0, stream>>>(P, x, VcTh, VcTm, VcTl);
  k_gram   <<<dim3(64),   b256, 0, stream>>>(P, Gm);
  k_cholinv<<<dim3(1), dim3(64), 0, stream>>>(Gm, Li);
  k_applyq <<<dim3(128),  b256, 0, stream>>>(Ub, P, Li);
  k_prep_u <<<dim3(128),  b256, 0, stream>>>(Ub, Uh, Ul, UTh, UTm, UTl);
  k_gtu    <<<dim3(64,8), b256, 0, stream>>>(W, x, UTh, UTm, UTl);
  k_colnorm<<<dim3(64),   b256, 0, stream>>>(W, Sv);
  k_vnorm  <<<dim3(1024), b256, 0, stream>>>(V, W, Sv);

  // ---- power iteration 2 ----
  k_prep_vct<<<dim3(64),  b256, 0, stream>>>(V, VcTh, VcTm, VcTl);
  k_zero   <<<dim3(2048), b256, 0, stream>>>(F, (int)nZero2);      // P, W, Gram
  k_gv     <<<dim3(64,8), b256, 0, stream>>>(P, x, VcTh, VcTm, VcTl);
  k_gram   <<<dim3(64),   b256, 0, stream>>>(P, Gm);
  k_cholinv<<<dim3(1), dim3(64), 0, stream>>>(Gm, Li);
  k_applyq <<<dim3(128),  b256, 0, stream>>>(Ub, P, Li);
  k_prep_u <<<dim3(128),  b256, 0, stream>>>(Ub, Uh, Ul, UTh, UTm, UTl);
  k_gtu    <<<dim3(64,8), b256, 0, stream>>>(W, x, UTh, UTm, UTl);
  k_colnorm<<<dim3(64),   b256, 0, stream>>>(W, Sv);               // Sv = S
  k_vnkv   <<<dim3(1024), b256, 0, stream>>>(V, KVTh, KVTl, W, Sv, scal+2);

  // ---- quantize factors + residual ----
  k_amax4<<<dim3(1024), b256, 0, stream>>>((const float4*)Ub, 131072, scal+1);
  k_qu   <<<dim3(2048), b256, 0, stream>>>(Aq, Ub, scal+1);
  k_qv   <<<dim3(64),   b256, 0, stream>>>(Vq, V, scal+2);
  k_res  <<<dim3(128,32), b256, 0, stream>>>(x, Uh, Ul, KVTh, KVTl, scal+3, Aq, 0);
  k_res  <<<dim3(128,32), b256, 0, stream>>>(x, Uh, Ul, KVTh, KVTl, scal+3, Aq, 1);

  // ---- low-rank fold + main GEMM ----
  k_m1  <<<dim3(64,8), b256, 0, stream>>>(M1, Vq, Bq);
  k_m2t <<<dim3(1024), b256, 0, stream>>>(Bq, M1, Sv, scal);
  k_gemm<<<dim3(32,64), b256, 0, stream>>>(out, Aq, Bq, bias, scal);
}